// Round 20
// baseline (7750.327 us; speedup 1.0000x reference)
//
#include <hip/hip_runtime.h>
#include <math.h>

#define QL 4
#define BB 8
#define NN 4096
#define DIMF 1024
#define HH 8
#define CC 1024
#define DH 128

#define MARGIN 0.06f

typedef __attribute__((ext_vector_type(4))) float f32x4;
typedef __attribute__((ext_vector_type(4))) int   i32x4v;
typedef __attribute__((ext_vector_type(8))) short s16x8;
typedef signed char c16 __attribute__((ext_vector_type(16)));

__device__ __forceinline__ unsigned short f2bf(float f) {
    unsigned int u = __float_as_uint(f);
    u = u + 0x7fffu + ((u >> 16) & 1u);
    return (unsigned short)(u >> 16);
}
__device__ __forceinline__ float bf2f(unsigned short b) {
    return __uint_as_float(((unsigned int)b) << 16);
}
__device__ __forceinline__ void dma16(const void* g, void* l) {
    __builtin_amdgcn_global_load_lds(
        (const __attribute__((address_space(1))) unsigned int*)g,
        (__attribute__((address_space(3))) unsigned int*)l, 16, 0, 0);
}
__device__ __forceinline__ i32x4v c2i(c16 v) { union { c16 c; i32x4v i; } u; u.c = v; return u.i; }
__device__ __forceinline__ c16 i2c(i32x4v v) { union { c16 c; i32x4v i; } u; u.i = v; return u.c; }

#define MFMA_I8(a, bb, c) c = __builtin_amdgcn_mfma_i32_16x16x64_i8(a, bb, c, 0, 0, 0)

// branchless top-2: m2 = max(min(m1,v), m2); strict > keeps first index
__device__ __forceinline__ void upd(float& m1, float& m2, int& mi, float v, int c) {
    m2 = fmaxf(fminf(m1, v), m2);
    if (v > m1) { m1 = v; mi = c; }
}

// ---------------------------------------------------------------------------
// Kernel A1: k = codes @ wk (bf16 hi/lo pair), v = codes @ wv (f32),
// + per-(q,h) panel max|k| via atomicMax (float-bits, values >= 0).
// ---------------------------------------------------------------------------
__global__ __launch_bounds__(128) void kv_kernel(
    const float* __restrict__ codes, const float* __restrict__ wk,
    const float* __restrict__ wv, unsigned short* __restrict__ khi,
    unsigned short* __restrict__ klo, float* __restrict__ vbuf,
    unsigned* __restrict__ skm)
{
    __shared__ float sc[8][128];
    __shared__ unsigned smx;
    int bid = blockIdx.x;
    int cg  = bid & 127;
    int qh  = bid >> 7;
    int t   = threadIdx.x;

    if (t == 0) smx = 0;
    const float* cbase = codes + ((size_t)qh * CC + (size_t)cg * 8) * DH;
    #pragma unroll
    for (int i = 0; i < 8; ++i) sc[i][t] = cbase[i * DH + t];
    __syncthreads();

    const float* wkb = wk + (size_t)qh * DH * DH;
    const float* wvb = wv + (size_t)qh * DH * DH;

    float ak[8], av[8];
    #pragma unroll
    for (int i = 0; i < 8; ++i) { ak[i] = 0.f; av[i] = 0.f; }

    for (int d = 0; d < DH; ++d) {
        float a = wkb[d * DH + t];
        float b = wvb[d * DH + t];
        #pragma unroll
        for (int i = 0; i < 8; ++i) {
            ak[i] = fmaf(sc[i][d], a, ak[i]);
            av[i] = fmaf(sc[i][d], b, av[i]);
        }
    }

    float m = 0.f;
    #pragma unroll
    for (int i = 0; i < 8; ++i) m = fmaxf(m, fabsf(ak[i]));
    atomicMax(&smx, __float_as_uint(m));

    size_t base = ((size_t)qh * CC + (size_t)cg * 8) * DH + t;
    #pragma unroll
    for (int i = 0; i < 8; ++i) {
        float f = ak[i];
        unsigned short hb = f2bf(f);
        unsigned short lb = f2bf(f - bf2f(hb));
        khi[base + (size_t)i * DH]  = hb;
        klo[base + (size_t)i * DH]  = lb;
        vbuf[base + (size_t)i * DH] = av[i];
    }
    __syncthreads();
    if (t == 0) atomicMax(&skm[qh], smx);
}

// ---------------------------------------------------------------------------
// Kernel A2: quantize k panels to int8 hi/lo MFMA B-fragments, IN-PLACE over
// the bf16 rows (write region [base, base+2048) of each ctile's 4KB region).
// Frag layout per ctile: [ks2][lane][16B], lane = kg*16+col, bytes = k-dims
// (ks2*64 + kg*16 + j) of code (ctile*16+col).  grid = 32 qh x 64 ctile.
// ---------------------------------------------------------------------------
__global__ __launch_bounds__(128) void quant_kernel(
    unsigned short* __restrict__ khi, unsigned short* __restrict__ klo,
    const unsigned* __restrict__ skm)
{
    __shared__ unsigned short shi[16][128];
    __shared__ unsigned short slo[16][128];
    const int bid   = blockIdx.x;
    const int qh    = bid >> 6;
    const int ctile = bid & 63;
    const int t     = threadIdx.x;

    {
        int row = t >> 3, seg = t & 7;
        const unsigned short* hs = khi + ((size_t)qh * CC + ctile * 16 + row) * DH + seg * 16;
        const unsigned short* ls = klo + ((size_t)qh * CC + ctile * 16 + row) * DH + seg * 16;
        *reinterpret_cast<s16x8*>(&shi[row][seg * 16])     = *reinterpret_cast<const s16x8*>(hs);
        *reinterpret_cast<s16x8*>(&shi[row][seg * 16 + 8]) = *reinterpret_cast<const s16x8*>(hs + 8);
        *reinterpret_cast<s16x8*>(&slo[row][seg * 16])     = *reinterpret_cast<const s16x8*>(ls);
        *reinterpret_cast<s16x8*>(&slo[row][seg * 16 + 8]) = *reinterpret_cast<const s16x8*>(ls + 8);
    }
    __syncthreads();

    const float inv = 126.f / __uint_as_float(skm[qh]);
    char* hdst = (char*)khi;
    char* ldst = (char*)klo;

    #pragma unroll
    for (int half = 0; half < 2; ++half) {
        int u    = t + half * 128;
        int ks2  = u >> 7;
        int term = (u >> 6) & 1;
        int lane = u & 63;
        int col  = lane & 15;
        int kg   = lane >> 4;
        int db   = ks2 * 64 + kg * 16;
        c16 ov;
        #pragma unroll
        for (int j = 0; j < 16; ++j) {
            float kv  = bf2f(shi[col][db + j]) + bf2f(slo[col][db + j]);
            float Kq  = kv * inv;
            float hif = rintf(Kq);
            float lof = rintf((Kq - hif) * 252.f);
            ov[j] = (signed char)(int)(term ? lof : hif);
        }
        size_t dst = ((size_t)qh * 64 + ctile) * 4096 + ks2 * 1024 + (size_t)lane * 16;
        *reinterpret_cast<c16*>((term ? ldst : hdst) + dst) = ov;
    }
}

// ---------------------------------------------------------------------------
// Kernel B: fused 4-layer residual memcodes, int8 fixed-point MFMA logits.
// grid = 2048 blocks (bid%8 == h -> XCD-pinned panels), 256 threads (4 waves).
// 128 tokens/block; wave w owns token tiles {w, w+4} (16 tokens each).
// Residual = per-token-scaled int8 hi/lo pair in regs (exact i32 MFMA dots).
// chunk = 32 codes (2 ctiles, 8KB), counted-vmcnt(2) + raw barriers.
// ---------------------------------------------------------------------------
__global__ __launch_bounds__(256, 2) void fused_kernel(
    const float* __restrict__ x, const unsigned short* __restrict__ khi,
    const unsigned short* __restrict__ klo, const unsigned* __restrict__ skm,
    const float* __restrict__ vbuf, const float* __restrict__ codes,
    const float* __restrict__ wk, const float* __restrict__ wv,
    float* __restrict__ out)
{
    __shared__ __align__(16) char kstage[2][8192]; // [buf][lc*4096 + term*2048 + ks2*1024 + lane*16]
    __shared__ int    chosen[128];
    __shared__ float  smax1[128];
    __shared__ int    flagged[128];
    __shared__ int    hist[QL][128];
    __shared__ float  srbuf[128];
    __shared__ int    nflag;
    __shared__ float  rbuf32[DH];
    __shared__ double rbuf64[DH];
    __shared__ double pbuf[DH];
    __shared__ int    cand[64];
    __shared__ int    ncand;
    __shared__ int    bestc;
    __shared__ double bestv;

    const int t  = threadIdx.x;
    const int w  = t >> 6;
    const int l  = t & 63;
    const int lr = l & 15;
    const int lg = l >> 4;

    const int bid = blockIdx.x;          // ((b*32 + nt)<<3) | h
    const int h   = bid & 7;
    const int nt  = (bid >> 3) & 31;
    const int b   = bid >> 8;
    const int n0  = nt * 128;

    // ---- residual as per-token-scaled int8 hi/lo A-fragments ----
    i32x4v aH[2][2], aL[2][2];     // [slot][ks2]
    float  sreg[2];
    #pragma unroll
    for (int s = 0; s < 2; ++s) {
        const int tok = (s * 4 + w) * 16 + lr;
        const float* xp = x + ((size_t)(b * NN + n0 + tok)) * DIMF + h * DH;
        float rr[2][16];
        #pragma unroll
        for (int ks2 = 0; ks2 < 2; ++ks2) {
            const float* p = xp + ks2 * 64 + lg * 16;
            #pragma unroll
            for (int q4 = 0; q4 < 4; ++q4) {
                float4 v4 = *reinterpret_cast<const float4*>(p + q4 * 4);
                rr[ks2][q4 * 4 + 0] = v4.x; rr[ks2][q4 * 4 + 1] = v4.y;
                rr[ks2][q4 * 4 + 2] = v4.z; rr[ks2][q4 * 4 + 3] = v4.w;
            }
        }
        float mx = 0.f;
        #pragma unroll
        for (int ks2 = 0; ks2 < 2; ++ks2)
            #pragma unroll
            for (int j = 0; j < 16; ++j) mx = fmaxf(mx, fabsf(rr[ks2][j]));
        mx = fmaxf(mx, __shfl_xor(mx, 16));
        mx = fmaxf(mx, __shfl_xor(mx, 32));
        float sv  = mx * (1.f / 126.f) + 1e-30f;
        float inv = 1.f / sv;
        #pragma unroll
        for (int ks2 = 0; ks2 < 2; ++ks2) {
            c16 hv, lv;
            #pragma unroll
            for (int j = 0; j < 16; ++j) {
                float Rq  = rr[ks2][j] * inv;
                float hif = rintf(Rq);
                float lof = rintf((Rq - hif) * 252.f);
                hv[j] = (signed char)(int)hif;
                lv[j] = (signed char)(int)lof;
            }
            aH[s][ks2] = c2i(hv); aL[s][ks2] = c2i(lv);
        }
        sreg[s] = sv;
        if (lg == 0) srbuf[tok] = sv;
    }
    if (t == 0) nflag = 0;
    __syncthreads();

    for (int q = 0; q < QL; ++q) {
        const char* khc8 = (const char*)khi + (size_t)(q * HH + h) * 262144;
        const char* klc8 = (const char*)klo + (size_t)(q * HH + h) * 262144;
        const float skG  = __uint_as_float(skm[q * HH + h]) * (1.f / 126.f);
        const float* vq  = vbuf + (size_t)(q * HH + h) * CC * DH;

        // wave w stages one 2KB piece per chunk: lc = w&1, term = w>>1
        auto stage2 = [&](int buf, int chunk) {
            const int cc = chunk * 2 + (w & 1);
            const char* g = ((w >> 1) ? klc8 : khc8) + (size_t)cc * 4096 + (size_t)l * 16;
            char* lb = &kstage[buf][0] + (w & 1) * 4096 + (w >> 1) * 2048;
            dma16(g,        lb);
            dma16(g + 1024, lb + 1024);
        };

        float bv[2][4], b2[2][4];
        int   bi[2][4];
        #pragma unroll
        for (int s = 0; s < 2; ++s)
            #pragma unroll
            for (int r = 0; r < 4; ++r) {
                bv[s][r] = -INFINITY; b2[s][r] = -INFINITY; bi[s][r] = 0;
            }

        // ---- prologue: issue chunk 0 ----
        stage2(0, 0);

        // ---- 32 chunks of 32 codes (2 ctiles each), counted-vmcnt ----
        for (int ct = 0; ct < 32; ++ct) {
            const int cur = ct & 1;
            if (ct < 31) {
                stage2(cur ^ 1, ct + 1);
                asm volatile("s_waitcnt vmcnt(2)" ::: "memory");
            } else {
                asm volatile("s_waitcnt vmcnt(0)" ::: "memory");
            }
            __builtin_amdgcn_sched_barrier(0);
            __builtin_amdgcn_s_barrier();      // chunk ct landed
            __builtin_amdgcn_sched_barrier(0);

            const char* Bb = &kstage[cur][0];
            #pragma unroll
            for (int lc = 0; lc < 2; ++lc) {
                const char* pb = Bb + lc * 4096 + l * 16;
                i32x4v bh0 = *reinterpret_cast<const i32x4v*>(pb);
                i32x4v bh1 = *reinterpret_cast<const i32x4v*>(pb + 1024);
                i32x4v bl0 = *reinterpret_cast<const i32x4v*>(pb + 2048);
                i32x4v bl1 = *reinterpret_cast<const i32x4v*>(pb + 3072);

                i32x4v hh0 = {0,0,0,0}, xx0 = {0,0,0,0};
                i32x4v hh1 = {0,0,0,0}, xx1 = {0,0,0,0};

                __builtin_amdgcn_s_setprio(1);
                MFMA_I8(aH[0][0], bh0, hh0); MFMA_I8(aH[1][0], bh0, hh1);
                MFMA_I8(aH[0][0], bl0, xx0); MFMA_I8(aH[1][0], bl0, xx1);
                MFMA_I8(aL[0][0], bh0, xx0); MFMA_I8(aL[1][0], bh0, xx1);
                MFMA_I8(aH[0][1], bh1, hh0); MFMA_I8(aH[1][1], bh1, hh1);
                MFMA_I8(aH[0][1], bl1, xx0); MFMA_I8(aH[1][1], bl1, xx1);
                MFMA_I8(aL[0][1], bh1, xx0); MFMA_I8(aL[1][1], bh1, xx1);
                __builtin_amdgcn_s_setprio(0);

                const int cb = (ct * 2 + lc) * 16 + lr;
                #pragma unroll
                for (int r = 0; r < 4; ++r) {
                    float u0 = (float)hh0[r] + (float)xx0[r] * (1.f / 252.f);
                    float u1 = (float)hh1[r] + (float)xx1[r] * (1.f / 252.f);
                    upd(bv[0][r], b2[0][r], bi[0][r], u0, cb);
                    upd(bv[1][r], b2[1][r], bi[1][r], u1, cb);
                }
            }

            __builtin_amdgcn_sched_barrier(0);
            __builtin_amdgcn_s_barrier();      // all waves done reading buf[cur]
            __builtin_amdgcn_sched_barrier(0);
        }

        // ---- cross-lane argmax reduce (unscaled u; same row => same scale) ----
        #pragma unroll
        for (int s = 0; s < 2; ++s) {
            #pragma unroll
            for (int r = 0; r < 4; ++r) {
                float m = bv[s][r]; float m2 = b2[s][r]; int mi = bi[s][r];
                #pragma unroll
                for (int off = 1; off <= 8; off <<= 1) {
                    float ov = __shfl_xor(m, off);
                    int   oi = __shfl_xor(mi, off);
                    float o2 = __shfl_xor(m2, off);
                    float nm2 = fmaxf(fmaxf(m2, o2), fminf(m, ov));
                    if (ov > m || (ov == m && oi < mi)) { m = ov; mi = oi; }
                    m2 = nm2;
                }
                if (lr == 0) {
                    int tok = (s * 4 + w) * 16 + lg * 4 + r;
                    float sf = srbuf[tok] * skG;
                    chosen[tok] = mi; smax1[tok] = m * sf;
                    int fl = ((m - m2) * sf < MARGIN) ? 1 : 0;
                    flagged[tok] = fl;
                    if (fl) atomicAdd(&nflag, 1);
                }
            }
        }
        __syncthreads();

        // ---- f64 rescue for near-tie tokens (rare; block-uniform) ----
        int nf = nflag;
        if (nf) {
            for (int tok = 0; tok < 128; ++tok) {
                if (!flagged[tok]) continue;
                if (t == 0) { ncand = 0; bestc = 0x7fffffff; bestv = -1e300; }
                // (b) exact f64 residual from x, codes, wv, history
                if (t < DH) {
                    double r = (double)x[((size_t)(b * NN + n0 + tok)) * DIMF + h * DH + t];
                    for (int qq = 0; qq < q; ++qq) {
                        int c = hist[qq][tok];
                        const float* crow = codes + ((size_t)(qq * HH + h) * CC + c) * DH;
                        const float* wcol = wv + (size_t)(qq * HH + h) * DH * DH + t;
                        double acc = 0.0;
                        for (int dd = 0; dd < DH; ++dd)
                            acc += (double)crow[dd] * (double)wcol[(size_t)dd * DH];
                        r -= acc;
                    }
                    rbuf64[t] = r;
                    rbuf32[t] = (float)r;
                }
                __syncthreads();
                // (a) fp32 prescan with exact residual vs QUANTIZED k (fast-path k)
                float thr = smax1[tok] - MARGIN;
                #pragma unroll
                for (int cc4 = 0; cc4 < 4; ++cc4) {
                    int c   = t * 4 + cc4;
                    int cct = c >> 4, col = c & 15;
                    const char* hb8 = khc8 + (size_t)cct * 4096;
                    const char* lb8 = klc8 + (size_t)cct * 4096;
                    float acc = 0.f;
                    for (int d = 0; d < DH; ++d) {
                        int ks2 = d >> 6, kg = (d & 63) >> 4, j = d & 15;
                        int off = ks2 * 1024 + (kg * 16 + col) * 16 + j;
                        float kq = skG * ((float)(int)(signed char)hb8[off] +
                                          (float)(int)(signed char)lb8[off] * (1.f / 252.f));
                        acc = fmaf(kq, rbuf32[d], acc);
                    }
                    if (acc >= thr) {
                        int p = atomicAdd(&ncand, 1);
                        if (p < 64) cand[p] = c;
                    }
                }
                __syncthreads();
                // (c) f64 rescore of candidates (exact np semantics + tie rule)
                int nc = ncand; if (nc > 64) nc = 64;
                for (int ci = 0; ci < nc; ++ci) {
                    int c = cand[ci];
                    if (t < DH) {
                        const float* crow = codes + ((size_t)(q * HH + h) * CC + c) * DH;
                        const float* wcol = wk + (size_t)(q * HH + h) * DH * DH + t;
                        double acc = 0.0;
                        for (int dd = 0; dd < DH; ++dd)
                            acc += (double)crow[dd] * (double)wcol[(size_t)dd * DH];
                        pbuf[t] = acc * rbuf64[t];
                    }
                    __syncthreads();
                    if (t == 0) {
                        double sm = 0.0;
                        for (int dd = 0; dd < DH; ++dd) sm += pbuf[dd];
                        if (sm > bestv || (sm == bestv && c < bestc)) { bestv = sm; bestc = c; }
                    }
                    __syncthreads();
                }
                if (t == 0) chosen[tok] = bestc;
                __syncthreads();
            }
        }

        // ---- finalize: history; reset flag counter ----
        if (t < 128) hist[q][t] = chosen[t];
        if (t == 0) nflag = 0;

        // ---- residual update: reconstruct f32, subtract v, requantize ----
        #pragma unroll
        for (int s = 0; s < 2; ++s) {
            const int tok = (s * 4 + w) * 16 + lr;
            const float* vrow = vq + (size_t)chosen[tok] * DH;
            float rr[2][16];
            #pragma unroll
            for (int ks2 = 0; ks2 < 2; ++ks2) {
                const float* p = vrow + ks2 * 64 + lg * 16;
                c16 hv = i2c(aH[s][ks2]);
                c16 lv = i2c(aL[s][ks2]);
                #pragma unroll
                for (int q4 = 0; q4 < 4; ++q4) {
                    float4 v4 = *reinterpret_cast<const float4*>(p + q4 * 4);
                    float vv[4] = {v4.x, v4.y, v4.z, v4.w};
                    #pragma unroll
                    for (int jj = 0; jj < 4; ++jj) {
                        int j = q4 * 4 + jj;
                        rr[ks2][j] = sreg[s] * ((float)(int)hv[j] +
                                     (float)(int)lv[j] * (1.f / 252.f)) - vv[jj];
                    }
                }
            }
            float mx = 0.f;
            #pragma unroll
            for (int ks2 = 0; ks2 < 2; ++ks2)
                #pragma unroll
                for (int j = 0; j < 16; ++j) mx = fmaxf(mx, fabsf(rr[ks2][j]));
            mx = fmaxf(mx, __shfl_xor(mx, 16));
            mx = fmaxf(mx, __shfl_xor(mx, 32));
            float sv  = mx * (1.f / 126.f) + 1e-30f;
            float inv = 1.f / sv;
            #pragma unroll
            for (int ks2 = 0; ks2 < 2; ++ks2) {
                c16 hv, lv;
                #pragma unroll
                for (int j = 0; j < 16; ++j) {
                    float Rq  = rr[ks2][j] * inv;
                    float hif = rintf(Rq);
                    float lof = rintf((Rq - hif) * 252.f);
                    hv[j] = (signed char)(int)hif;
                    lv[j] = (signed char)(int)lof;
                }
                aH[s][ks2] = c2i(hv); aL[s][ks2] = c2i(lv);
            }
            sreg[s] = sv;
            if (lg == 0) srbuf[tok] = sv;
        }
        __syncthreads();   // srbuf/chosen settled; kstage free for next layer
    }

    // ---- epilogue: quantized_out = x - residual (reconstructed) ----
    #pragma unroll
    for (int s = 0; s < 2; ++s) {
        const int tok = (s * 4 + w) * 16 + lr;
        const float* xp = x + ((size_t)(b * NN + n0 + tok)) * DIMF + h * DH;
        float* op = out + ((size_t)(b * NN + n0 + tok)) * DIMF + h * DH;
        #pragma unroll
        for (int ks2 = 0; ks2 < 2; ++ks2) {
            const float* p = xp + ks2 * 64 + lg * 16;
            c16 hv = i2c(aH[s][ks2]);
            c16 lv = i2c(aL[s][ks2]);
            #pragma unroll
            for (int q4 = 0; q4 < 4; ++q4) {
                float4 xv = *reinterpret_cast<const float4*>(p + q4 * 4);
                float4 ov;
                float* o = &ov.x;
                float  xx[4] = {xv.x, xv.y, xv.z, xv.w};
                #pragma unroll
                for (int jj = 0; jj < 4; ++jj) {
                    int j = q4 * 4 + jj;
                    o[jj] = xx[jj] - sreg[s] * ((float)(int)hv[j] +
                             (float)(int)lv[j] * (1.f / 252.f));
                }
                *reinterpret_cast<float4*>(op + ks2 * 64 + lg * 16 + q4 * 4) = ov;
            }
        }
    }

    // ---- dense index write: one float4 per token ----
    __syncthreads();
    if (t < 128) {
        float4 iv;
        iv.x = (float)hist[0][t];
        iv.y = (float)hist[1][t];
        iv.z = (float)hist[2][t];
        iv.w = (float)hist[3][t];
        float* ip = out + (size_t)BB * NN * DIMF +
                    (((size_t)(b * HH + h) * NN) + n0 + t) * QL;
        *reinterpret_cast<float4*>(ip) = iv;
    }
}

extern "C" void kernel_launch(void* const* d_in, const int* in_sizes, int n_in,
                              void* d_out, int out_size, void* d_ws, size_t ws_size,
                              hipStream_t stream) {
    const float* x     = (const float*)d_in[0];
    const float* codes = (const float*)d_in[1];
    const float* wk    = (const float*)d_in[2];
    const float* wv    = (const float*)d_in[3];
    float* out  = (float*)d_out;

    float* vbuf = (float*)d_ws;                                                // 16.8 MiB
    unsigned short* khi = (unsigned short*)(vbuf + (size_t)QL * HH * CC * DH); // 8.4 MiB
    unsigned short* klo = khi + (size_t)QL * HH * CC * DH;                     // 8.4 MiB
    unsigned* skm = (unsigned*)(klo + (size_t)QL * HH * CC * DH);              // 128 B

    hipMemsetAsync(skm, 0, QL * HH * sizeof(unsigned), stream);
    kv_kernel<<<QL * HH * CC / 8, 128, 0, stream>>>(codes, wk, wv, khi, klo, vbuf, skm);
    quant_kernel<<<QL * HH * 64, 128, 0, stream>>>(khi, klo, skm);
    fused_kernel<<<BB * HH * (NN / 128), 256, 0, stream>>>(x, khi, klo, skm, vbuf,
                                                           codes, wk, wv, out);
}

// Round 21
// 1176.197 us; speedup vs baseline: 6.5893x; 6.5893x over previous
//
#include <hip/hip_runtime.h>
#include <math.h>

#define QL 4
#define BB 8
#define NN 4096
#define DIMF 1024
#define HH 8
#define CC 1024
#define DH 128

#define MARGIN 4e-3f

typedef __attribute__((ext_vector_type(4))) float f32x4;
typedef __attribute__((ext_vector_type(8))) short s16x8;

__device__ __forceinline__ unsigned short f2bf(float f) {
    unsigned int u = __float_as_uint(f);
    u = u + 0x7fffu + ((u >> 16) & 1u);
    return (unsigned short)(u >> 16);
}
__device__ __forceinline__ float bf2f(unsigned short b) {
    return __uint_as_float(((unsigned int)b) << 16);
}
__device__ __forceinline__ void dma16(const void* g, void* l) {
    __builtin_amdgcn_global_load_lds(
        (const __attribute__((address_space(1))) unsigned int*)g,
        (__attribute__((address_space(3))) unsigned int*)l, 16, 0, 0);
}

#define MFMA(a, bb, c) c = __builtin_amdgcn_mfma_f32_16x16x32_bf16(a, bb, c, 0, 0, 0)

// branchless top-2: m2 = max(min(m1,v), m2); strict > keeps first index
__device__ __forceinline__ void upd(float& m1, float& m2, int& mi, float v, int c) {
    m2 = fmaxf(fminf(m1, v), m2);
    if (v > m1) { m1 = v; mi = c; }
}

// ---------------------------------------------------------------------------
// Kernel A: k = codes @ wk (split bf16 hi/lo), v = codes @ wv (f32).
// ---------------------------------------------------------------------------
__global__ __launch_bounds__(128) void kv_kernel(
    const float* __restrict__ codes, const float* __restrict__ wk,
    const float* __restrict__ wv, unsigned short* __restrict__ khi,
    unsigned short* __restrict__ klo, float* __restrict__ vbuf)
{
    __shared__ float sc[8][128];
    int bid = blockIdx.x;
    int cg  = bid & 127;
    int qh  = bid >> 7;
    int t   = threadIdx.x;

    const float* cbase = codes + ((size_t)qh * CC + (size_t)cg * 8) * DH;
    #pragma unroll
    for (int i = 0; i < 8; ++i) sc[i][t] = cbase[i * DH + t];
    __syncthreads();

    const float* wkb = wk + (size_t)qh * DH * DH;
    const float* wvb = wv + (size_t)qh * DH * DH;

    float ak[8], av[8];
    #pragma unroll
    for (int i = 0; i < 8; ++i) { ak[i] = 0.f; av[i] = 0.f; }

    for (int d = 0; d < DH; ++d) {
        float a = wkb[d * DH + t];
        float b = wvb[d * DH + t];
        #pragma unroll
        for (int i = 0; i < 8; ++i) {
            ak[i] = fmaf(sc[i][d], a, ak[i]);
            av[i] = fmaf(sc[i][d], b, av[i]);
        }
    }

    size_t base = ((size_t)qh * CC + (size_t)cg * 8) * DH + t;
    #pragma unroll
    for (int i = 0; i < 8; ++i) {
        float f = ak[i];
        unsigned short hb = f2bf(f);
        unsigned short lb = f2bf(f - bf2f(hb));
        khi[base + (size_t)i * DH]  = hb;
        klo[base + (size_t)i * DH]  = lb;
        vbuf[base + (size_t)i * DH] = av[i];
    }
}

// ---------------------------------------------------------------------------
// Kernel B: fused 4-layer residual memcodes, 3-term bf16-split logits.
// grid = 4096 blocks (bid%8 == h -> XCD-pinned panels), 256 threads (4 waves).
// 64 tokens/block; wave w owns ONE token tile (16 tokens).
// chunk = 16 codes; THREE 8KB LDS buffers, 1-ahead prefetch, ONE raw barrier
// per chunk (WAR-safe: buf[(ct+1)%3] last read as chunk ct-2, retired before
// barrier(ct-1), and dma for ct+1 issues only after barrier(ct-1)).
// LDS ~29KB -> 5 blocks/CU at the measured 80-VGPR allocation.
// ---------------------------------------------------------------------------
__global__ __launch_bounds__(256, 2) void fused_kernel(
    const float* __restrict__ x, const unsigned short* __restrict__ khi,
    const unsigned short* __restrict__ klo, const float* __restrict__ vbuf,
    const float* __restrict__ codes, const float* __restrict__ wk,
    const float* __restrict__ wv, float* __restrict__ out)
{
    __shared__ __align__(16) char kstage[3][8192];  // [buf][hi 4K | lo 4K]
    __shared__ int    chosen[64];
    __shared__ float  smax1[64];
    __shared__ int    flagged[64];
    __shared__ int    hist[QL][64];
    __shared__ int    nflag;
    __shared__ float  rbuf32[DH];
    __shared__ double rbuf64[DH];
    __shared__ double pbuf[DH];
    __shared__ int    cand[64];
    __shared__ int    ncand;
    __shared__ int    bestc;
    __shared__ double bestv;

    const int t  = threadIdx.x;
    const int w  = t >> 6;
    const int l  = t & 63;
    const int lr = l & 15;
    const int lg = l >> 4;

    const int bid = blockIdx.x;          // ((b*64 + nt)<<3) | h
    const int h   = bid & 7;
    const int nt  = (bid >> 3) & 63;
    const int b   = bid >> 9;
    const int n0  = nt * 64;

    // DMA per-lane pre-swizzled source offsets; wave parity selects the
    // rows-4..7-mod-8 variant (validated pair with the read swizzle).
    const int colE  = ((l & 15) << 4) ^ ((l >> 4) << 4) ^ (((l >> 3) & 1) << 5);
    const int loffE = ((l >> 4) << 8) + colE;
    const int loffW = (w & 1) ? (loffE ^ 0x40) : loffE;

    // ---- residual as bf16 hi/lo A-fragments: [ks] (one 16-token tile) ----
    s16x8 rhi[4], rlo[4];
    {
        const int tok = w * 16 + lr;
        const float* xp = x + ((size_t)(b * NN + n0 + tok)) * DIMF + h * DH;
        #pragma unroll
        for (int ks = 0; ks < 4; ++ks) {
            const float* p = xp + ks * 32 + lg * 8;
            float4 a = *reinterpret_cast<const float4*>(p);
            float4 c = *reinterpret_cast<const float4*>(p + 4);
            float vv[8] = {a.x, a.y, a.z, a.w, c.x, c.y, c.z, c.w};
            s16x8 hi8, lo8;
            #pragma unroll
            for (int j = 0; j < 8; ++j) {
                unsigned short hb = f2bf(vv[j]);
                unsigned short lb = f2bf(vv[j] - bf2f(hb));
                hi8[j] = (short)hb; lo8[j] = (short)lb;
            }
            rhi[ks] = hi8; rlo[ks] = lo8;
        }
    }
    if (t == 0) nflag = 0;
    __syncthreads();

    for (int q = 0; q < QL; ++q) {
        const unsigned short* khq = khi + (size_t)(q * HH + h) * CC * DH;
        const unsigned short* klq = klo + (size_t)(q * HH + h) * CC * DH;
        const float* vq = vbuf + (size_t)(q * HH + h) * CC * DH;
        const char* khc = (const char*)khq;
        const char* klc = (const char*)klq;

        // each wave stages 1KB of hi + 1KB of lo per 16-code chunk
        auto stage2 = [&](int buf, int chunk) {
            const char* gh = khc + chunk * 4096 + w * 1024;
            const char* gl = klc + chunk * 4096 + w * 1024;
            char* lb = &kstage[buf][0] + w * 1024;
            dma16(gh + loffW, lb);
            dma16(gl + loffW, lb + 4096);
        };

        float bv[4], b2[4];
        int   bi[4];
        #pragma unroll
        for (int r = 0; r < 4; ++r) {
            bv[r] = -INFINITY; b2[r] = -INFINITY; bi[r] = 0;
        }

        // ---- prologue: issue chunk 0 ----
        stage2(0, 0);

        // ---- 64 chunks of 16 codes; single barrier per chunk ----
        for (int ct = 0; ct < 64; ++ct) {
            const int cur = ct % 3;
            if (ct < 63) {
                stage2((ct + 1) % 3, ct + 1);
                asm volatile("s_waitcnt vmcnt(2)" ::: "memory");
            } else {
                asm volatile("s_waitcnt vmcnt(0)" ::: "memory");
            }
            __builtin_amdgcn_sched_barrier(0);
            __builtin_amdgcn_s_barrier();      // chunk ct landed, all waves
            __builtin_amdgcn_sched_barrier(0);

            const char* Bb = &kstage[cur][0];
            f32x4 a00 = {0.f,0.f,0.f,0.f};

            #pragma unroll
            for (int ks = 0; ks < 4; ++ks) {
                const int swz = ((ks * 64 + lg * 16) ^ ((lr & 7) << 4)) ^ ((ks >> 1) << 5);
                const char* p0 = Bb + lr * 256 + swz;
                s16x8 bh0 = *reinterpret_cast<const s16x8*>(p0);
                s16x8 bl0 = *reinterpret_cast<const s16x8*>(p0 + 4096);

                __builtin_amdgcn_s_setprio(1);
                MFMA(rhi[ks], bh0, a00);
                MFMA(rlo[ks], bh0, a00);
                MFMA(rhi[ks], bl0, a00);
                __builtin_amdgcn_s_setprio(0);
            }

            {
                const int cb = ct * 16 + lr;
                #pragma unroll
                for (int r = 0; r < 4; ++r)
                    upd(bv[r], b2[r], bi[r], a00[r], cb);
            }
        }

        // ---- cross-lane argmax reduce (16 lanes = 16 codes per token) ----
        #pragma unroll
        for (int r = 0; r < 4; ++r) {
            float m = bv[r]; float m2 = b2[r]; int mi = bi[r];
            #pragma unroll
            for (int off = 1; off <= 8; off <<= 1) {
                float ov = __shfl_xor(m, off);
                int   oi = __shfl_xor(mi, off);
                float o2 = __shfl_xor(m2, off);
                float nm2 = fmaxf(fmaxf(m2, o2), fminf(m, ov));
                if (ov > m || (ov == m && oi < mi)) { m = ov; mi = oi; }
                m2 = nm2;
            }
            if (lr == 0) {
                int tok = w * 16 + lg * 4 + r;
                chosen[tok] = mi; smax1[tok] = m;
                int fl = (m - m2 < MARGIN) ? 1 : 0;
                flagged[tok] = fl;
                if (fl) atomicAdd(&nflag, 1);
            }
        }
        __syncthreads();

        // ---- f64 rescue for near-tie tokens (rare; block-uniform) ----
        int nf = nflag;
        if (nf) {
            for (int tok = 0; tok < 64; ++tok) {
                if (!flagged[tok]) continue;
                if (t == 0) { ncand = 0; bestc = 0x7fffffff; bestv = -1e300; }
                // (b) exact f64 residual from x, codes, wv, history
                if (t < DH) {
                    double r = (double)x[((size_t)(b * NN + n0 + tok)) * DIMF + h * DH + t];
                    for (int qq = 0; qq < q; ++qq) {
                        int c = hist[qq][tok];
                        const float* crow = codes + ((size_t)(qq * HH + h) * CC + c) * DH;
                        const float* wcol = wv + (size_t)(qq * HH + h) * DH * DH + t;
                        double acc = 0.0;
                        for (int dd = 0; dd < DH; ++dd)
                            acc += (double)crow[dd] * (double)wcol[(size_t)dd * DH];
                        r -= acc;
                    }
                    rbuf64[t] = r;
                    rbuf32[t] = (float)r;
                }
                __syncthreads();
                // (a) fp32 prescan with exact residual (khi+klo = fast-path k)
                float thr = smax1[tok] - MARGIN;
                #pragma unroll
                for (int cc4 = 0; cc4 < 4; ++cc4) {
                    int c = t * 4 + cc4;
                    const unsigned short* kh = khq + (size_t)c * DH;
                    const unsigned short* kl = klq + (size_t)c * DH;
                    float acc = 0.f;
                    for (int d = 0; d < DH; ++d)
                        acc = fmaf(bf2f(kh[d]) + bf2f(kl[d]), rbuf32[d], acc);
                    if (acc >= thr) {
                        int p = atomicAdd(&ncand, 1);
                        if (p < 64) cand[p] = c;
                    }
                }
                __syncthreads();
                // (c) f64 rescore of candidates (exact np semantics + tie rule)
                int nc = ncand; if (nc > 64) nc = 64;
                for (int ci = 0; ci < nc; ++ci) {
                    int c = cand[ci];
                    if (t < DH) {
                        const float* crow = codes + ((size_t)(q * HH + h) * CC + c) * DH;
                        const float* wcol = wk + (size_t)(q * HH + h) * DH * DH + t;
                        double acc = 0.0;
                        for (int dd = 0; dd < DH; ++dd)
                            acc += (double)crow[dd] * (double)wcol[(size_t)dd * DH];
                        pbuf[t] = acc * rbuf64[t];
                    }
                    __syncthreads();
                    if (t == 0) {
                        double sm = 0.0;
                        for (int dd = 0; dd < DH; ++dd) sm += pbuf[dd];
                        if (sm > bestv || (sm == bestv && c < bestc)) { bestv = sm; bestc = c; }
                    }
                    __syncthreads();
                }
                if (t == 0) chosen[tok] = bestc;
                __syncthreads();
            }
        }

        // ---- finalize: history; reset flag counter ----
        if (t < 64) hist[q][t] = chosen[t];
        if (t == 0) nflag = 0;

        // ---- residual -= v[chosen] (in-register, re-split) ----
        {
            const int tok = w * 16 + lr;
            const float* vrow = vq + (size_t)chosen[tok] * DH;
            #pragma unroll
            for (int ks = 0; ks < 4; ++ks) {
                const float* p = vrow + ks * 32 + lg * 8;
                float4 a = *reinterpret_cast<const float4*>(p);
                float4 c = *reinterpret_cast<const float4*>(p + 4);
                float vv[8] = {a.x, a.y, a.z, a.w, c.x, c.y, c.z, c.w};
                s16x8 hi8 = rhi[ks], lo8 = rlo[ks], nh, nl;
                #pragma unroll
                for (int j = 0; j < 8; ++j) {
                    float f = bf2f((unsigned short)hi8[j]) +
                              bf2f((unsigned short)lo8[j]) - vv[j];
                    unsigned short hb = f2bf(f);
                    nh[j] = (short)hb;
                    nl[j] = (short)f2bf(f - bf2f(hb));
                }
                rhi[ks] = nh; rlo[ks] = nl;
            }
        }
        __syncthreads();   // chosen reads done; kstage free for next layer
    }

    // ---- epilogue: quantized_out = x - residual ----
    {
        const int tok = w * 16 + lr;
        const float* xp = x + ((size_t)(b * NN + n0 + tok)) * DIMF + h * DH;
        float* op = out + ((size_t)(b * NN + n0 + tok)) * DIMF + h * DH;
        #pragma unroll
        for (int ks = 0; ks < 4; ++ks) {
            const float* p = xp + ks * 32 + lg * 8;
            float4 a = *reinterpret_cast<const float4*>(p);
            float4 c = *reinterpret_cast<const float4*>(p + 4);
            s16x8 hi8 = rhi[ks], lo8 = rlo[ks];
            float4 o0, o1;
            o0.x = a.x - (bf2f((unsigned short)hi8[0]) + bf2f((unsigned short)lo8[0]));
            o0.y = a.y - (bf2f((unsigned short)hi8[1]) + bf2f((unsigned short)lo8[1]));
            o0.z = a.z - (bf2f((unsigned short)hi8[2]) + bf2f((unsigned short)lo8[2]));
            o0.w = a.w - (bf2f((unsigned short)hi8[3]) + bf2f((unsigned short)lo8[3]));
            o1.x = c.x - (bf2f((unsigned short)hi8[4]) + bf2f((unsigned short)lo8[4]));
            o1.y = c.y - (bf2f((unsigned short)hi8[5]) + bf2f((unsigned short)lo8[5]));
            o1.z = c.z - (bf2f((unsigned short)hi8[6]) + bf2f((unsigned short)lo8[6]));
            o1.w = c.w - (bf2f((unsigned short)hi8[7]) + bf2f((unsigned short)lo8[7]));
            *reinterpret_cast<float4*>(op + ks * 32 + lg * 8)     = o0;
            *reinterpret_cast<float4*>(op + ks * 32 + lg * 8 + 4) = o1;
        }
    }

    // ---- dense index write: one float4 per token ----
    __syncthreads();
    if (t < 64) {
        float4 iv;
        iv.x = (float)hist[0][t];
        iv.y = (float)hist[1][t];
        iv.z = (float)hist[2][t];
        iv.w = (float)hist[3][t];
        float* ip = out + (size_t)BB * NN * DIMF +
                    (((size_t)(b * HH + h) * NN) + n0 + t) * QL;
        *reinterpret_cast<float4*>(ip) = iv;
    }
}

extern "C" void kernel_launch(void* const* d_in, const int* in_sizes, int n_in,
                              void* d_out, int out_size, void* d_ws, size_t ws_size,
                              hipStream_t stream) {
    const float* x     = (const float*)d_in[0];
    const float* codes = (const float*)d_in[1];
    const float* wk    = (const float*)d_in[2];
    const float* wv    = (const float*)d_in[3];
    float* out  = (float*)d_out;

    float* vbuf = (float*)d_ws;                                                // 16 MiB
    unsigned short* khi = (unsigned short*)(vbuf + (size_t)QL * HH * CC * DH); // 8 MiB
    unsigned short* klo = khi + (size_t)QL * HH * CC * DH;                     // 8 MiB

    kv_kernel<<<QL * HH * CC / 8, 128, 0, stream>>>(codes, wk, wv, khi, klo, vbuf);
    fused_kernel<<<BB * HH * (NN / 64), 256, 0, stream>>>(x, khi, klo, vbuf,
                                                          codes, wk, wv, out);
}

// Round 22
// 1066.566 us; speedup vs baseline: 7.2666x; 1.1028x over previous
//
#include <hip/hip_runtime.h>
#include <math.h>

#define QL 4
#define BB 8
#define NN 4096
#define DIMF 1024
#define HH 8
#define CC 1024
#define DH 128

#define MARGIN 4e-3f

typedef __attribute__((ext_vector_type(4))) float f32x4;
typedef __attribute__((ext_vector_type(8))) short s16x8;

__device__ __forceinline__ unsigned short f2bf(float f) {
    unsigned int u = __float_as_uint(f);
    u = u + 0x7fffu + ((u >> 16) & 1u);
    return (unsigned short)(u >> 16);
}
__device__ __forceinline__ float bf2f(unsigned short b) {
    return __uint_as_float(((unsigned int)b) << 16);
}
__device__ __forceinline__ void dma16(const void* g, void* l) {
    __builtin_amdgcn_global_load_lds(
        (const __attribute__((address_space(1))) unsigned int*)g,
        (__attribute__((address_space(3))) unsigned int*)l, 16, 0, 0);
}

#define MFMA(a, bb, c) c = __builtin_amdgcn_mfma_f32_16x16x32_bf16(a, bb, c, 0, 0, 0)

// branchless top-2: m2 = max(min(m1,v), m2); strict > keeps first index
__device__ __forceinline__ void upd(float& m1, float& m2, int& mi, float v, int c) {
    m2 = fmaxf(fminf(m1, v), m2);
    if (v > m1) { m1 = v; mi = c; }
}

// ---------------------------------------------------------------------------
// Kernel A: k = codes @ wk (split bf16 hi/lo), v = codes @ wv (f32).
// ---------------------------------------------------------------------------
__global__ __launch_bounds__(128) void kv_kernel(
    const float* __restrict__ codes, const float* __restrict__ wk,
    const float* __restrict__ wv, unsigned short* __restrict__ khi,
    unsigned short* __restrict__ klo, float* __restrict__ vbuf)
{
    __shared__ float sc[8][128];
    int bid = blockIdx.x;
    int cg  = bid & 127;
    int qh  = bid >> 7;
    int t   = threadIdx.x;

    const float* cbase = codes + ((size_t)qh * CC + (size_t)cg * 8) * DH;
    #pragma unroll
    for (int i = 0; i < 8; ++i) sc[i][t] = cbase[i * DH + t];
    __syncthreads();

    const float* wkb = wk + (size_t)qh * DH * DH;
    const float* wvb = wv + (size_t)qh * DH * DH;

    float ak[8], av[8];
    #pragma unroll
    for (int i = 0; i < 8; ++i) { ak[i] = 0.f; av[i] = 0.f; }

    for (int d = 0; d < DH; ++d) {
        float a = wkb[d * DH + t];
        float b = wvb[d * DH + t];
        #pragma unroll
        for (int i = 0; i < 8; ++i) {
            ak[i] = fmaf(sc[i][d], a, ak[i]);
            av[i] = fmaf(sc[i][d], b, av[i]);
        }
    }

    size_t base = ((size_t)qh * CC + (size_t)cg * 8) * DH + t;
    #pragma unroll
    for (int i = 0; i < 8; ++i) {
        float f = ak[i];
        unsigned short hb = f2bf(f);
        unsigned short lb = f2bf(f - bf2f(hb));
        khi[base + (size_t)i * DH]  = hb;
        klo[base + (size_t)i * DH]  = lb;
        vbuf[base + (size_t)i * DH] = av[i];
    }
}

// ---------------------------------------------------------------------------
// Kernel B: fused 4-layer residual memcodes, 3-term bf16-split logits.
// grid = 4096 blocks (bid%8 == h -> XCD-pinned panels), 256 threads (4 waves).
// 64 tokens/block; wave w owns ONE token tile (16 tokens) -> per-wave live
// state ~95 VGPRs (no pressure at the 128 budget) so residency/wave count
// can rise. chunk = 32 codes, kstage 2x16KB (~37.4KB LDS -> 4 blocks/CU).
// Counted-vmcnt(4) pipeline with raw barriers (r12 sync structure).
// Best measured configuration of the session (r18: 1071 us).
// ---------------------------------------------------------------------------
__global__ __launch_bounds__(256, 2) void fused_kernel(
    const float* __restrict__ x, const unsigned short* __restrict__ khi,
    const unsigned short* __restrict__ klo, const float* __restrict__ vbuf,
    const float* __restrict__ codes, const float* __restrict__ wk,
    const float* __restrict__ wv, float* __restrict__ out)
{
    __shared__ __align__(16) char kstage[2][16384];  // [buf][hi 8K | lo 8K]
    __shared__ int    chosen[64];
    __shared__ float  smax1[64];
    __shared__ int    flagged[64];
    __shared__ int    hist[QL][64];
    __shared__ int    nflag;
    __shared__ float  rbuf32[DH];
    __shared__ double rbuf64[DH];
    __shared__ double pbuf[DH];
    __shared__ int    cand[64];
    __shared__ int    ncand;
    __shared__ int    bestc;
    __shared__ double bestv;

    const int t  = threadIdx.x;
    const int w  = t >> 6;
    const int l  = t & 63;
    const int lr = l & 15;
    const int lg = l >> 4;

    const int bid = blockIdx.x;          // ((b*64 + nt)<<3) | h
    const int h   = bid & 7;
    const int nt  = (bid >> 3) & 63;
    const int b   = bid >> 9;
    const int n0  = nt * 64;

    // DMA per-lane pre-swizzled source offsets (pairs with read swizzle below)
    const int colE  = ((l & 15) << 4) ^ ((l >> 4) << 4) ^ (((l >> 3) & 1) << 5);
    const int loffE = ((l >> 4) << 8) + colE;
    const int loffO = loffE ^ 0x40;

    // ---- residual as bf16 hi/lo A-fragments: [ks] (one 16-token tile) ----
    s16x8 rhi[4], rlo[4];
    {
        const int tok = w * 16 + lr;
        const float* xp = x + ((size_t)(b * NN + n0 + tok)) * DIMF + h * DH;
        #pragma unroll
        for (int ks = 0; ks < 4; ++ks) {
            const float* p = xp + ks * 32 + lg * 8;
            float4 a = *reinterpret_cast<const float4*>(p);
            float4 c = *reinterpret_cast<const float4*>(p + 4);
            float vv[8] = {a.x, a.y, a.z, a.w, c.x, c.y, c.z, c.w};
            s16x8 hi8, lo8;
            #pragma unroll
            for (int j = 0; j < 8; ++j) {
                unsigned short hb = f2bf(vv[j]);
                unsigned short lb = f2bf(vv[j] - bf2f(hb));
                hi8[j] = (short)hb; lo8[j] = (short)lb;
            }
            rhi[ks] = hi8; rlo[ks] = lo8;
        }
    }
    if (t == 0) nflag = 0;
    __syncthreads();

    for (int q = 0; q < QL; ++q) {
        const unsigned short* khq = khi + (size_t)(q * HH + h) * CC * DH;
        const unsigned short* klq = klo + (size_t)(q * HH + h) * CC * DH;
        const float* vq = vbuf + (size_t)(q * HH + h) * CC * DH;
        const char* khc = (const char*)khq;
        const char* klc = (const char*)klq;

        auto stage4 = [&](int buf, int chunk) {
            const char* gh = khc + chunk * 8192 + w * 2048;
            const char* gl = klc + chunk * 8192 + w * 2048;
            char* lb = &kstage[buf][0] + w * 2048;
            dma16(gh + loffE, lb);
            dma16(gh + 1024 + loffO, lb + 1024);
            dma16(gl + loffE, lb + 8192);
            dma16(gl + 1024 + loffO, lb + 8192 + 1024);
        };

        float bv[4], b2[4];
        int   bi[4];
        #pragma unroll
        for (int r = 0; r < 4; ++r) {
            bv[r] = -INFINITY; b2[r] = -INFINITY; bi[r] = 0;
        }

        // ---- prologue: issue chunk 0 ----
        stage4(0, 0);

        // ---- 32 chunks of 32 codes, counted-vmcnt pipeline ----
        for (int ct = 0; ct < 32; ++ct) {
            const int cur = ct & 1;
            if (ct < 31) {
                stage4(cur ^ 1, ct + 1);
                asm volatile("s_waitcnt vmcnt(4)" ::: "memory");
            } else {
                asm volatile("s_waitcnt vmcnt(0)" ::: "memory");
            }
            __builtin_amdgcn_sched_barrier(0);
            __builtin_amdgcn_s_barrier();      // all waves: chunk ct landed
            __builtin_amdgcn_sched_barrier(0);

            const char* Bb = &kstage[cur][0];
            f32x4 a00 = {0.f,0.f,0.f,0.f}, a01 = {0.f,0.f,0.f,0.f};

            #pragma unroll
            for (int ks = 0; ks < 4; ++ks) {
                const int swz = ((ks * 64 + lg * 16) ^ ((lr & 7) << 4)) ^ ((ks >> 1) << 5);
                const char* p0 = Bb + (lr)      * 256 + swz;
                const char* p1 = Bb + (16 + lr) * 256 + swz;
                s16x8 bh0 = *reinterpret_cast<const s16x8*>(p0);
                s16x8 bh1 = *reinterpret_cast<const s16x8*>(p1);
                s16x8 bl0 = *reinterpret_cast<const s16x8*>(p0 + 8192);
                s16x8 bl1 = *reinterpret_cast<const s16x8*>(p1 + 8192);

                __builtin_amdgcn_s_setprio(1);
                MFMA(rhi[ks], bh0, a00); MFMA(rhi[ks], bh1, a01);
                MFMA(rlo[ks], bh0, a00); MFMA(rlo[ks], bh1, a01);
                MFMA(rhi[ks], bl0, a00); MFMA(rhi[ks], bl1, a01);
                __builtin_amdgcn_s_setprio(0);
            }

            {
                const int cb = ct * 32 + lr;
                #pragma unroll
                for (int r = 0; r < 4; ++r) {
                    upd(bv[r], b2[r], bi[r], a00[r], cb);
                    upd(bv[r], b2[r], bi[r], a01[r], cb + 16);
                }
            }

            __builtin_amdgcn_sched_barrier(0);
            __builtin_amdgcn_s_barrier();      // all waves done reading buf[cur]
            __builtin_amdgcn_sched_barrier(0);
        }

        // ---- cross-lane argmax reduce (16 lanes = 16 codes per token) ----
        #pragma unroll
        for (int r = 0; r < 4; ++r) {
            float m = bv[r]; float m2 = b2[r]; int mi = bi[r];
            #pragma unroll
            for (int off = 1; off <= 8; off <<= 1) {
                float ov = __shfl_xor(m, off);
                int   oi = __shfl_xor(mi, off);
                float o2 = __shfl_xor(m2, off);
                float nm2 = fmaxf(fmaxf(m2, o2), fminf(m, ov));
                if (ov > m || (ov == m && oi < mi)) { m = ov; mi = oi; }
                m2 = nm2;
            }
            if (lr == 0) {
                int tok = w * 16 + lg * 4 + r;
                chosen[tok] = mi; smax1[tok] = m;
                int fl = (m - m2 < MARGIN) ? 1 : 0;
                flagged[tok] = fl;
                if (fl) atomicAdd(&nflag, 1);
            }
        }
        __syncthreads();

        // ---- f64 rescue for near-tie tokens (rare; block-uniform) ----
        int nf = nflag;
        if (nf) {
            for (int tok = 0; tok < 64; ++tok) {
                if (!flagged[tok]) continue;
                if (t == 0) { ncand = 0; bestc = 0x7fffffff; bestv = -1e300; }
                // (b) exact f64 residual from x, codes, wv, history
                if (t < DH) {
                    double r = (double)x[((size_t)(b * NN + n0 + tok)) * DIMF + h * DH + t];
                    for (int qq = 0; qq < q; ++qq) {
                        int c = hist[qq][tok];
                        const float* crow = codes + ((size_t)(qq * HH + h) * CC + c) * DH;
                        const float* wcol = wv + (size_t)(qq * HH + h) * DH * DH + t;
                        double acc = 0.0;
                        for (int dd = 0; dd < DH; ++dd)
                            acc += (double)crow[dd] * (double)wcol[(size_t)dd * DH];
                        r -= acc;
                    }
                    rbuf64[t] = r;
                    rbuf32[t] = (float)r;
                }
                __syncthreads();
                // (a) fp32 prescan with exact residual (khi+klo = fast-path k)
                float thr = smax1[tok] - MARGIN;
                #pragma unroll
                for (int cc4 = 0; cc4 < 4; ++cc4) {
                    int c = t * 4 + cc4;
                    const unsigned short* kh = khq + (size_t)c * DH;
                    const unsigned short* kl = klq + (size_t)c * DH;
                    float acc = 0.f;
                    for (int d = 0; d < DH; ++d)
                        acc = fmaf(bf2f(kh[d]) + bf2f(kl[d]), rbuf32[d], acc);
                    if (acc >= thr) {
                        int p = atomicAdd(&ncand, 1);
                        if (p < 64) cand[p] = c;
                    }
                }
                __syncthreads();
                // (c) f64 rescore of candidates (exact np semantics + tie rule)
                int nc = ncand; if (nc > 64) nc = 64;
                for (int ci = 0; ci < nc; ++ci) {
                    int c = cand[ci];
                    if (t < DH) {
                        const float* crow = codes + ((size_t)(q * HH + h) * CC + c) * DH;
                        const float* wcol = wk + (size_t)(q * HH + h) * DH * DH + t;
                        double acc = 0.0;
                        for (int dd = 0; dd < DH; ++dd)
                            acc += (double)crow[dd] * (double)wcol[(size_t)dd * DH];
                        pbuf[t] = acc * rbuf64[t];
                    }
                    __syncthreads();
                    if (t == 0) {
                        double sm = 0.0;
                        for (int dd = 0; dd < DH; ++dd) sm += pbuf[dd];
                        if (sm > bestv || (sm == bestv && c < bestc)) { bestv = sm; bestc = c; }
                    }
                    __syncthreads();
                }
                if (t == 0) chosen[tok] = bestc;
                __syncthreads();
            }
        }

        // ---- finalize: history; reset flag counter ----
        if (t < 64) hist[q][t] = chosen[t];
        if (t == 0) nflag = 0;

        // ---- residual -= v[chosen] (in-register, re-split) ----
        {
            const int tok = w * 16 + lr;
            const float* vrow = vq + (size_t)chosen[tok] * DH;
            #pragma unroll
            for (int ks = 0; ks < 4; ++ks) {
                const float* p = vrow + ks * 32 + lg * 8;
                float4 a = *reinterpret_cast<const float4*>(p);
                float4 c = *reinterpret_cast<const float4*>(p + 4);
                float vv[8] = {a.x, a.y, a.z, a.w, c.x, c.y, c.z, c.w};
                s16x8 hi8 = rhi[ks], lo8 = rlo[ks], nh, nl;
                #pragma unroll
                for (int j = 0; j < 8; ++j) {
                    float f = bf2f((unsigned short)hi8[j]) +
                              bf2f((unsigned short)lo8[j]) - vv[j];
                    unsigned short hb = f2bf(f);
                    nh[j] = (short)hb;
                    nl[j] = (short)f2bf(f - bf2f(hb));
                }
                rhi[ks] = nh; rlo[ks] = nl;
            }
        }
        __syncthreads();   // chosen reads done; kstage free for next layer
    }

    // ---- epilogue: quantized_out = x - residual ----
    {
        const int tok = w * 16 + lr;
        const float* xp = x + ((size_t)(b * NN + n0 + tok)) * DIMF + h * DH;
        float* op = out + ((size_t)(b * NN + n0 + tok)) * DIMF + h * DH;
        #pragma unroll
        for (int ks = 0; ks < 4; ++ks) {
            const float* p = xp + ks * 32 + lg * 8;
            float4 a = *reinterpret_cast<const float4*>(p);
            float4 c = *reinterpret_cast<const float4*>(p + 4);
            s16x8 hi8 = rhi[ks], lo8 = rlo[ks];
            float4 o0, o1;
            o0.x = a.x - (bf2f((unsigned short)hi8[0]) + bf2f((unsigned short)lo8[0]));
            o0.y = a.y - (bf2f((unsigned short)hi8[1]) + bf2f((unsigned short)lo8[1]));
            o0.z = a.z - (bf2f((unsigned short)hi8[2]) + bf2f((unsigned short)lo8[2]));
            o0.w = a.w - (bf2f((unsigned short)hi8[3]) + bf2f((unsigned short)lo8[3]));
            o1.x = c.x - (bf2f((unsigned short)hi8[4]) + bf2f((unsigned short)lo8[4]));
            o1.y = c.y - (bf2f((unsigned short)hi8[5]) + bf2f((unsigned short)lo8[5]));
            o1.z = c.z - (bf2f((unsigned short)hi8[6]) + bf2f((unsigned short)lo8[6]));
            o1.w = c.w - (bf2f((unsigned short)hi8[7]) + bf2f((unsigned short)lo8[7]));
            *reinterpret_cast<float4*>(op + ks * 32 + lg * 8)     = o0;
            *reinterpret_cast<float4*>(op + ks * 32 + lg * 8 + 4) = o1;
        }
    }

    // ---- dense index write: one float4 per token ----
    __syncthreads();
    if (t < 64) {
        float4 iv;
        iv.x = (float)hist[0][t];
        iv.y = (float)hist[1][t];
        iv.z = (float)hist[2][t];
        iv.w = (float)hist[3][t];
        float* ip = out + (size_t)BB * NN * DIMF +
                    (((size_t)(b * HH + h) * NN) + n0 + t) * QL;
        *reinterpret_cast<float4*>(ip) = iv;
    }
}

extern "C" void kernel_launch(void* const* d_in, const int* in_sizes, int n_in,
                              void* d_out, int out_size, void* d_ws, size_t ws_size,
                              hipStream_t stream) {
    const float* x     = (const float*)d_in[0];
    const float* codes = (const float*)d_in[1];
    const float* wk    = (const float*)d_in[2];
    const float* wv    = (const float*)d_in[3];
    float* out  = (float*)d_out;

    float* vbuf = (float*)d_ws;                                                // 16 MiB
    unsigned short* khi = (unsigned short*)(vbuf + (size_t)QL * HH * CC * DH); // 8 MiB
    unsigned short* klo = khi + (size_t)QL * HH * CC * DH;                     // 8 MiB

    kv_kernel<<<QL * HH * CC / 8, 128, 0, stream>>>(codes, wk, wv, khi, klo, vbuf);
    fused_kernel<<<BB * HH * (NN / 64), 256, 0, stream>>>(x, khi, klo, vbuf,
                                                          codes, wk, wv, out);
}